// Round 7
// baseline (314.822 us; speedup 1.0000x reference)
//
#include <hip/hip_runtime.h>
#include <cstdint>
#include <cstddef>

#define HH 128
#define SLOPE 0.01f

typedef __attribute__((ext_vector_type(8))) __bf16 bf16x8;
typedef __attribute__((ext_vector_type(8))) unsigned short ushort8v;
typedef __attribute__((ext_vector_type(4))) float f32x4;

__device__ __forceinline__ float lrelu(float x) { return x >= 0.f ? x : SLOPE * x; }
__device__ __forceinline__ unsigned short f2b(float f) {
  union { float f; unsigned u; } v; v.f = f;
  unsigned r = v.u + 0x7fffu + ((v.u >> 16) & 1u);  // round-to-nearest-even
  return (unsigned short)(r >> 16);
}
__device__ __forceinline__ float b2f(unsigned short u) {
  union { unsigned u; float f; } v; v.u = ((unsigned)u) << 16; return v.f;
}

// LDS tile layout with XOR swizzle: element (r,k) of a [rows]x128 bf16 tile lives at
// lofs(r,k). 16B chunks (8 ushorts) stay contiguous; chunk index ^= (r&15).
__device__ __forceinline__ int lofs(int r, int k) {
  return (r << 7) + ((((k >> 3) ^ r) & 15) << 3) + (k & 7);
}

// Single-wave LDS write->read sync: wave is lockstep (one PC); lgkmcnt(0) drain +
// compiler fence is sufficient for within-wave cross-lane exchange.
#define WAVE_SYNC() asm volatile("s_waitcnt lgkmcnt(0)" ::: "memory")

// ---------------- CSR build ----------------

__global__ __launch_bounds__(256) void count_kernel(const int* __restrict__ dst,
                                                    int* __restrict__ cnt, int nE) {
  int e = blockIdx.x * 256 + threadIdx.x;
  if (e < nE) atomicAdd(&cnt[dst[e]], 1);
}

__global__ __launch_bounds__(1024) void scan1_kernel(int* __restrict__ cnt,
                                                     int* __restrict__ rowptr,
                                                     int* __restrict__ bsum,
                                                     float* __restrict__ dinv, int n) {
  __shared__ int wsum[16];
  const int tid = threadIdx.x;
  const int lane = tid & 63, wid = tid >> 6;
  int i = blockIdx.x * 1024 + tid;
  int v = (i < n) ? cnt[i] : 0;
  int x = v;
#pragma unroll
  for (int off = 1; off < 64; off <<= 1) {
    int y = __shfl_up(x, off, 64);
    if (lane >= off) x += y;
  }
  if (lane == 63) wsum[wid] = x;
  __syncthreads();
  if (tid == 0) {
    int s = 0;
#pragma unroll
    for (int w = 0; w < 16; ++w) { int t = wsum[w]; wsum[w] = s; s += t; }
    bsum[blockIdx.x] = s;
  }
  __syncthreads();
  if (i < n) {
    rowptr[i] = wsum[wid] + x - v;  // local exclusive
    dinv[i] = rsqrtf((float)v + 1.0f);
    cnt[i] = 0;
  }
}

__global__ __launch_bounds__(64) void scan2_kernel(int* __restrict__ bsum, int nb,
                                                   int* __restrict__ rowptr, int n, int E) {
  int lane = threadIdx.x;
  int v = (lane < nb) ? bsum[lane] : 0;
  int x = v;
#pragma unroll
  for (int off = 1; off < 64; off <<= 1) {
    int y = __shfl_up(x, off, 64);
    if (lane >= off) x += y;
  }
  if (lane < nb) bsum[lane] = x - v;  // exclusive
  if (lane == 0) rowptr[n] = E;
}

__global__ __launch_bounds__(1024) void scan3_kernel(int* __restrict__ rowptr,
                                                     const int* __restrict__ bsum, int n) {
  int i = blockIdx.x * 1024 + threadIdx.x;
  if (i < n) rowptr[i] += bsum[blockIdx.x];
}

// csr entry: .x = src node, .y = norm (float bits)
__global__ __launch_bounds__(256) void fill_kernel(const int* __restrict__ src,
                                                   const int* __restrict__ dst,
                                                   const int* __restrict__ rowptr,
                                                   int* __restrict__ cursor,
                                                   const float* __restrict__ dinv,
                                                   int2* __restrict__ csr, int nE) {
  int e = blockIdx.x * 256 + threadIdx.x;
  if (e >= nE) return;
  int d = dst[e], s = src[e];
  int pos = rowptr[d] + atomicAdd(&cursor[d], 1);
  int2 ent;
  ent.x = s;
  ent.y = __float_as_int(dinv[s] * dinv[d]);
  csr[pos] = ent;
}

// ---------------- weight pack: B-fragment order for mfma 16x16x32 ----------------
__global__ __launch_bounds__(256) void pack_kernel(const float* W0, const float* W1,
                                                   const float* W2, const float* W3,
                                                   const float* W4, const float* W5,
                                                   unsigned short* __restrict__ out) {
  const float* Ws[6] = {W0, W1, W2, W3, W4, W5};
  const float* W = Ws[blockIdx.y];
  int f = blockIdx.x * 256 + threadIdx.x;  // 0..16383
  int j = f & 7, L = (f >> 3) & 63, c = (f >> 9) & 7, t = f >> 12;
  int k = t * 32 + (L >> 4) * 8 + j;
  int n = c * 16 + (L & 15);
  out[(size_t)blockIdx.y * 16384 + f] = f2b(W[k * HH + n]);
}

// ---------------- shared device helpers ----------------

// 16-row MFMA stage; B-fragments from the block-shared LDS weight copy.
// Fragment f at bytes [f*1024 + lane*16] -> ds_read_b128, 1KB contiguous per
// wave access = conflict-free (2 lanes/bank aliasing is free).
__device__ __forceinline__ void mfma_ldsW(const bf16x8 af[4],
                                          const unsigned short* __restrict__ Wl,
                                          int lane, f32x4 acc[8]) {
#pragma unroll
  for (int c = 0; c < 8; ++c) acc[c] = (f32x4){0.f, 0.f, 0.f, 0.f};
#pragma unroll
  for (int t = 0; t < 4; ++t) {
    bf16x8 wf[8];
#pragma unroll
    for (int c = 0; c < 8; ++c) wf[c] = *(const bf16x8*)&Wl[(t * 8 + c) * 512 + lane * 8];
#pragma unroll
    for (int c = 0; c < 8; ++c)
      acc[c] = __builtin_amdgcn_mfma_f32_16x16x32_bf16(af[t], wf[c], acc[c], 0, 0, 0);
  }
}

// A-fragments from a 16-row swizzled LDS tile (arow = lane&15).
__device__ __forceinline__ void lds_afrags16(const unsigned short* __restrict__ Tl,
                                             int m, int quad, bf16x8 af[4]) {
#pragma unroll
  for (int t = 0; t < 4; ++t)
    af[t] = *(const bf16x8*)&Tl[lofs(m, t * 32 + quad * 8)];
}

// ---------------- GEMM: A(fp32)[nrows,128] @ Wp -> bf16 out ----------------
// 4 waves/block, 16 rows/wave. Weights staged ONCE per block into 32KB LDS
// (cuts per-dispatch weight traffic 4x vs per-wave global streaming), then read
// as conflict-free ds_read_b128. LDS 32KB -> up to 4-5 blocks/CU.

__global__ __launch_bounds__(256) void gemm_conv(const float* __restrict__ A,
                                                 const unsigned short* __restrict__ Wp,
                                                 unsigned short* __restrict__ out, int nrows) {
  __shared__ __align__(16) unsigned short Wl[16384];
  const int tid = threadIdx.x;
  const int lane = tid & 63, wave = tid >> 6;
  const int row0 = blockIdx.x * 64 + wave * 16;
  const int m = lane & 15, quad = lane >> 4;

  // cooperative weight stage: 8 x uint4 per thread (linear layout preserved)
  uint4 pw[8];
#pragma unroll
  for (int i = 0; i < 8; ++i) pw[i] = ((const uint4*)Wp)[i * 256 + tid];

  // A fragments straight from global fp32, converted in-register
  const int gr = row0 + m;
  const bool rok = gr < nrows;
  const float* Arow = A + (size_t)gr * HH;
  bf16x8 af[4];
#pragma unroll
  for (int t = 0; t < 4; ++t) {
    const int k = t * 32 + quad * 8;
    float4 lo = make_float4(0.f, 0.f, 0.f, 0.f), hi = lo;
    if (rok) {
      lo = *(const float4*)(Arow + k);
      hi = *(const float4*)(Arow + k + 4);
    }
    union { ushort8v u; bf16x8 b; } cv;
    cv.u[0] = f2b(lo.x); cv.u[1] = f2b(lo.y); cv.u[2] = f2b(lo.z); cv.u[3] = f2b(lo.w);
    cv.u[4] = f2b(hi.x); cv.u[5] = f2b(hi.y); cv.u[6] = f2b(hi.z); cv.u[7] = f2b(hi.w);
    af[t] = cv.b;
  }

#pragma unroll
  for (int i = 0; i < 8; ++i) ((uint4*)Wl)[i * 256 + tid] = pw[i];
  __syncthreads();  // weights visible to all waves

  f32x4 acc[8];
  mfma_ldsW(af, Wl, lane, acc);

#pragma unroll
  for (int c = 0; c < 8; ++c) {
    int col = c * 16 + m;
#pragma unroll
    for (int g = 0; g < 4; ++g) {
      int row = row0 + quad * 4 + g;
      if (row < nrows) out[(size_t)row * HH + col] = f2b(acc[c][g]);
    }
  }
}

// ---------------- agg: one wave per node ----------------
// out = leaky(sum norm*h[src] + self*dinv^2 + bias (+res fp32)); fp32 or bf16 out.

template <int RES, int OUTBF>
__global__ __launch_bounds__(256) void agg_kernel(const unsigned short* __restrict__ h,
                                                  const int* __restrict__ rowptr,
                                                  const int2* __restrict__ csr,
                                                  const float* __restrict__ dinv,
                                                  const float* __restrict__ bias,
                                                  const float* __restrict__ res,
                                                  void* __restrict__ outv, int n) {
  int node = blockIdx.x * 4 + (threadIdx.x >> 6);
  if (node >= n) return;
  int lane = threadIdx.x & 63;
  int c = lane << 1;
  int j = rowptr[node], end = rowptr[node + 1];
  float ax = 0.f, ay = 0.f;
  // 8-deep unroll: 8 outstanding gather loads per lane
  for (; j + 8 <= end; j += 8) {
    int2 e[8];
    ushort2 r[8];
#pragma unroll
    for (int q = 0; q < 8; ++q) e[q] = csr[j + q];
#pragma unroll
    for (int q = 0; q < 8; ++q) r[q] = *(const ushort2*)(h + (size_t)e[q].x * HH + c);
#pragma unroll
    for (int q = 0; q < 8; ++q) {
      float nv = __int_as_float(e[q].y);
      ax = fmaf(b2f(r[q].x), nv, ax); ay = fmaf(b2f(r[q].y), nv, ay);
    }
  }
  for (; j + 2 <= end; j += 2) {
    int2 e0 = csr[j], e1 = csr[j + 1];
    ushort2 r0 = *(const ushort2*)(h + (size_t)e0.x * HH + c);
    ushort2 r1 = *(const ushort2*)(h + (size_t)e1.x * HH + c);
    float n0 = __int_as_float(e0.y), n1 = __int_as_float(e1.y);
    ax = fmaf(b2f(r0.x), n0, ax); ay = fmaf(b2f(r0.y), n0, ay);
    ax = fmaf(b2f(r1.x), n1, ax); ay = fmaf(b2f(r1.y), n1, ay);
  }
  if (j < end) {
    int2 e0 = csr[j];
    float n0 = __int_as_float(e0.y);
    ushort2 r0 = *(const ushort2*)(h + (size_t)e0.x * HH + c);
    ax = fmaf(b2f(r0.x), n0, ax); ay = fmaf(b2f(r0.y), n0, ay);
  }
  float di = dinv[node], d2 = di * di;
  ushort2 hs = *(const ushort2*)(h + (size_t)node * HH + c);
  float2 b = *(const float2*)(bias + c);
  float ox = ax + b2f(hs.x) * d2 + b.x;
  float oy = ay + b2f(hs.y) * d2 + b.y;
  if (RES) {
    float2 r = *(const float2*)(res + (size_t)node * HH + c);
    ox += r.x; oy += r.y;
  }
  ox = lrelu(ox); oy = lrelu(oy);
  if (OUTBF) {
    ushort2 o; o.x = f2b(ox); o.y = f2b(oy);
    *(ushort2*)((unsigned short*)outv + (size_t)node * HH + c) = o;
  } else {
    *(float2*)((float*)outv + (size_t)node * HH + c) = make_float2(ox, oy);
  }
}

// ---------------- fusedMLP: 4-GEMM chain, block-shared weight buffer ----------------
// 4 waves/block, 16 rows/wave. ONE 32KB LDS weight buffer, refilled per stage:
// next-stage weights prefetched into regs DURING current stage's MFMAs, then
// ds_written between a barrier pair (done-reading / now-visible). Cuts weight
// traffic 4x vs r6's per-wave streaming while keeping 0-conflict reads.
// Tiles stay wave-private (Ta/Tb 4KB each); gen via float4->bf16 regs parked in
// Tb (r6 trick); biases via 2 float4 loads -> BI. LDS total 72KB -> 2 blocks/CU.
// stage 1:  m  = leaky(f2@Wm1+bm1)                     Ta -> Tb
// stage 2:  h3 = leaky(m@Wm2+bm2 + f2); p=0.5*(h3+gen) Tb,Ta -> Ta
// stage 3:  q  = leaky(p@Wp1+bp1)                      Ta -> Tb
// stage 4:  out= leaky(q@Wp2+bp2)                      Tb -> fp32 global

__global__ __launch_bounds__(256) void fusedMLP(const unsigned short* __restrict__ f2bf,
                                                const unsigned short* __restrict__ Wm1p,
                                                const unsigned short* __restrict__ Wm2p,
                                                const unsigned short* __restrict__ Wp1p,
                                                const unsigned short* __restrict__ Wp2p,
                                                const float* __restrict__ bm1,
                                                const float* __restrict__ bm2,
                                                const float* __restrict__ bp1,
                                                const float* __restrict__ bp2,
                                                const float* __restrict__ gen,
                                                float* __restrict__ out, int n) {
  __shared__ __align__(16) unsigned short Wl[16384];      // 32KB shared, refilled per stage
  __shared__ __align__(16) unsigned short Ta[4][16 * HH]; // 4 x 4KB wave tiles
  __shared__ __align__(16) unsigned short Tb[4][16 * HH]; // 4 x 4KB wave tiles
  __shared__ __align__(16) float Bi[4][4 * HH];           // 4 x 2KB biases
  const int tid = threadIdx.x;
  const int lane = tid & 63, wave = tid >> 6;
  const int row0 = blockIdx.x * 64 + wave * 16;
  const int m = lane & 15, quad = lane >> 4;
  unsigned short* TA = Ta[wave];
  unsigned short* TB = Tb[wave];
  float* BI = Bi[wave];

  // --- W1 staging loads first (8 x uint4 per thread) ---
  uint4 pw[8];
#pragma unroll
  for (int i = 0; i < 8; ++i) pw[i] = ((const uint4*)Wm1p)[i * 256 + tid];

  // --- f2 tile -> TA (swizzled), 4 x 16B per lane ---
#pragma unroll
  for (int i = 0; i < 4; ++i) {
    int idx = i * 64 + lane;            // 16B-chunk id 0..255
    int r = idx >> 4, k = (idx & 15) << 3;
    int gr = row0 + r;
    ushort8v v = {0, 0, 0, 0, 0, 0, 0, 0};
    if (gr < n) v = *(const ushort8v*)(f2bf + (size_t)gr * HH + k);
    *(ushort8v*)&TA[lofs(r, k)] = v;
  }

  // --- gen -> bf16 regs in staging-chunk layout (held until stage 2) ---
  ushort4 genb[8];
#pragma unroll
  for (int i = 0; i < 8; ++i) {
    int idx = i * 64 + lane;            // float4-chunk id 0..511
    int r = idx >> 5, c4 = (idx & 31) << 2;
    int gr = row0 + r;
    float4 v = make_float4(0.f, 0.f, 0.f, 0.f);
    if (gr < n) v = *(const float4*)(gen + (size_t)gr * HH + c4);
    genb[i].x = f2b(v.x); genb[i].y = f2b(v.y); genb[i].z = f2b(v.z); genb[i].w = f2b(v.w);
  }

  // --- all 4 biases -> BI, 2 x float4 per lane; layout [mat*128 + col] ---
  {
    const float* b01 = (lane < 32) ? bm1 : bm2;
    const float* b23 = (lane < 32) ? bp1 : bp2;
    int col = (lane & 31) << 2;
    float4 v0 = *(const float4*)(b01 + col);
    float4 v1 = *(const float4*)(b23 + col);
    *(float4*)&BI[lane * 4] = v0;         // lane<32 -> bm1, else bm2
    *(float4*)&BI[256 + lane * 4] = v1;   // lane<32 -> bp1, else bp2
  }

  // --- write W1 into Wl ---
#pragma unroll
  for (int i = 0; i < 8; ++i) ((uint4*)Wl)[i * 256 + tid] = pw[i];
  __syncthreads();  // B1: W1 + tiles + biases visible

  bf16x8 af[4];
  f32x4 acc[8];
  float bv[8];

  // ---- stage 1: m = leaky(f2@Wm1+bm1), Ta -> Tb ----
#pragma unroll
  for (int cc = 0; cc < 8; ++cc) bv[cc] = BI[cc * 16 + m];
  lds_afrags16(TA, m, quad, af);
  // prefetch W2 (hides under stage-1 MFMAs)
#pragma unroll
  for (int i = 0; i < 8; ++i) pw[i] = ((const uint4*)Wm2p)[i * 256 + tid];
  mfma_ldsW(af, Wl, lane, acc);
#pragma unroll
  for (int cc = 0; cc < 8; ++cc) {
    int col = cc * 16 + m;
#pragma unroll
    for (int g = 0; g < 4; ++g)
      TB[lofs(quad * 4 + g, col)] = f2b(lrelu(acc[cc][g] + bv[cc]));
  }
  __syncthreads();  // B2: all waves done reading W1
#pragma unroll
  for (int i = 0; i < 8; ++i) ((uint4*)Wl)[i * 256 + tid] = pw[i];  // W2 in
  // prefetch W3
#pragma unroll
  for (int i = 0; i < 8; ++i) pw[i] = ((const uint4*)Wp1p)[i * 256 + tid];
  __syncthreads();  // B3: W2 visible (also orders Tb writes < Tb reads)

  // ---- stage 2: h3 = leaky(m@Wm2+bm2+f2); p = 0.5*(h3+gen), Tb,Ta -> Ta ----
#pragma unroll
  for (int cc = 0; cc < 8; ++cc) bv[cc] = BI[128 + cc * 16 + m];
  lds_afrags16(TB, m, quad, af);  // consume m into regs
  WAVE_SYNC();                    // af loaded before TB is overwritten
  // park gen (regs) into TB, staging layout
#pragma unroll
  for (int i = 0; i < 8; ++i) {
    int idx = i * 64 + lane;
    int r = idx >> 5, c4 = (idx & 31) << 2;
    *(ushort4*)&TB[lofs(r, c4)] = genb[i];
  }
  mfma_ldsW(af, Wl, lane, acc);
  WAVE_SYNC();                    // gen writes visible for epilogue reads
#pragma unroll
  for (int cc = 0; cc < 8; ++cc) {
    int col = cc * 16 + m;
#pragma unroll
    for (int g = 0; g < 4; ++g) {
      int lr = quad * 4 + g;
      float f2v = b2f(TA[lofs(lr, col)]);   // residual (same-lane slot)
      float v = lrelu(acc[cc][g] + bv[cc] + f2v);
      float gv = b2f(TB[lofs(lr, col)]);    // gen parked in TB
      TA[lofs(lr, col)] = f2b(0.5f * (v + gv));
    }
  }
  __syncthreads();  // B4: all waves done reading W2
#pragma unroll
  for (int i = 0; i < 8; ++i) ((uint4*)Wl)[i * 256 + tid] = pw[i];  // W3 in
  // prefetch W4
#pragma unroll
  for (int i = 0; i < 8; ++i) pw[i] = ((const uint4*)Wp2p)[i * 256 + tid];
  __syncthreads();  // B5: W3 visible (also orders Ta writes < Ta reads)

  // ---- stage 3: q = leaky(p@Wp1+bp1), Ta -> Tb (gen in TB dead) ----
#pragma unroll
  for (int cc = 0; cc < 8; ++cc) bv[cc] = BI[256 + cc * 16 + m];
  lds_afrags16(TA, m, quad, af);
  mfma_ldsW(af, Wl, lane, acc);
#pragma unroll
  for (int cc = 0; cc < 8; ++cc) {
    int col = cc * 16 + m;
#pragma unroll
    for (int g = 0; g < 4; ++g)
      TB[lofs(quad * 4 + g, col)] = f2b(lrelu(acc[cc][g] + bv[cc]));
  }
  __syncthreads();  // B6: all waves done reading W3
#pragma unroll
  for (int i = 0; i < 8; ++i) ((uint4*)Wl)[i * 256 + tid] = pw[i];  // W4 in
  __syncthreads();  // B7: W4 visible (also orders Tb writes < Tb reads)

  // ---- stage 4: out = leaky(q@Wp2+bp2), Tb -> global fp32 ----
#pragma unroll
  for (int cc = 0; cc < 8; ++cc) bv[cc] = BI[384 + cc * 16 + m];
  lds_afrags16(TB, m, quad, af);
  mfma_ldsW(af, Wl, lane, acc);
#pragma unroll
  for (int cc = 0; cc < 8; ++cc) {
    int col = cc * 16 + m;
#pragma unroll
    for (int g = 0; g < 4; ++g) {
      int row = row0 + quad * 4 + g;
      if (row < n) out[(size_t)row * HH + col] = lrelu(acc[cc][g] + bv[cc]);
    }
  }
}

// ---------------- launcher ----------------

extern "C" void kernel_launch(void* const* d_in, const int* in_sizes, int n_in,
                              void* d_out, int out_size, void* d_ws, size_t ws_size,
                              hipStream_t stream) {
  const float* x   = (const float*)d_in[0];
  const int* ei    = (const int*)d_in[1];
  const float* gen = (const float*)d_in[2];
  const float* Wc1 = (const float*)d_in[3];
  const float* bc1 = (const float*)d_in[4];
  const float* Wc2 = (const float*)d_in[5];
  const float* bc2 = (const float*)d_in[6];
  const float* Wm1 = (const float*)d_in[7];
  const float* bm1 = (const float*)d_in[8];
  const float* Wm2 = (const float*)d_in[9];
  const float* bm2 = (const float*)d_in[10];
  const float* Wp1 = (const float*)d_in[11];
  const float* bp1 = (const float*)d_in[12];
  const float* Wp2 = (const float*)d_in[13];
  const float* bp2 = (const float*)d_in[14];

  const int N = in_sizes[0] / HH;
  const int E = in_sizes[1] / 2;
  const int* src = ei;
  const int* dst = ei + E;

  char* ws = (char*)d_ws;
  size_t off = 0;
  auto alloc = [&](size_t bytes) { void* p = ws + off; off += (bytes + 255) & ~(size_t)255; return p; };
  float* dinv            = (float*)alloc((size_t)N * 4);
  int*   rowptr          = (int*)  alloc((size_t)(N + 1) * 4);
  int*   cursor          = (int*)  alloc((size_t)N * 4);
  int*   bsum            = (int*)  alloc((size_t)64 * 4);
  int2*  csr             = (int2*) alloc((size_t)E * 8);
  unsigned short* h_bf   = (unsigned short*)alloc((size_t)N * HH * 2);
  unsigned short* t2_bf  = (unsigned short*)alloc((size_t)N * HH * 2);
  unsigned short* f2_bf  = (unsigned short*)alloc((size_t)N * HH * 2);
  float* f1_f32          = (float*)alloc((size_t)N * HH * 4);
  unsigned short* packed = (unsigned short*)alloc((size_t)6 * 16384 * 2);
  float* fOut = (float*)d_out;

  const int cblocks = (N + 63) / 64;      // 4 waves x 16 rows per 256-thr block
  const int eblocks = (E + 255) / 256;
  const int ablocks = (N + 3) / 4;
  const int sblocks = (N + 1023) / 1024;  // <= 64 for N <= 65536

  // weight packing
  pack_kernel<<<dim3(64, 6), 256, 0, stream>>>(Wc1, Wc2, Wm1, Wm2, Wp1, Wp2, packed);

  // CSR build
  hipMemsetAsync(cursor, 0, (size_t)N * 4, stream);
  count_kernel<<<eblocks, 256, 0, stream>>>(dst, cursor, E);
  scan1_kernel<<<sblocks, 1024, 0, stream>>>(cursor, rowptr, bsum, dinv, N);
  scan2_kernel<<<1, 64, 0, stream>>>(bsum, sblocks, rowptr, N, E);
  scan3_kernel<<<sblocks, 1024, 0, stream>>>(rowptr, bsum, N);
  fill_kernel<<<eblocks, 256, 0, stream>>>(src, dst, rowptr, cursor, dinv, csr, E);

  // conv1: h_bf = bf16(x @ Wc1)
  gemm_conv<<<cblocks, 256, 0, stream>>>(x, packed + 0 * 16384, h_bf, N);
  // agg1: f1 = leaky(agg(h_bf)+self+bc1)  [fp32]
  agg_kernel<0, 0><<<ablocks, 256, 0, stream>>>(h_bf, rowptr, csr, dinv, bc1, nullptr, f1_f32, N);
  // conv2: t2 = bf16(f1 @ Wc2)
  gemm_conv<<<cblocks, 256, 0, stream>>>(f1_f32, packed + 1 * 16384, t2_bf, N);
  // agg2: f2 = leaky(agg(t2)+self+bc2+f1)  [bf16 — only consumed as bf16]
  agg_kernel<1, 1><<<ablocks, 256, 0, stream>>>(t2_bf, rowptr, csr, dinv, bc2, f1_f32, f2_bf, N);
  // fusedMLP: MLP + interp + proj -> d_out
  fusedMLP<<<cblocks, 256, 0, stream>>>(f2_bf,
                                        packed + 2 * 16384, packed + 3 * 16384,
                                        packed + 4 * 16384, packed + 5 * 16384,
                                        bm1, bm2, bp1, bp2, gen, fOut, N);
}

// Round 8
// 291.324 us; speedup vs baseline: 1.0807x; 1.0807x over previous
//
#include <hip/hip_runtime.h>
#include <cstdint>
#include <cstddef>

#define HH 128
#define SLOPE 0.01f

typedef __attribute__((ext_vector_type(8))) __bf16 bf16x8;
typedef __attribute__((ext_vector_type(8))) unsigned short ushort8v;
typedef __attribute__((ext_vector_type(4))) float f32x4;

__device__ __forceinline__ float lrelu(float x) { return x >= 0.f ? x : SLOPE * x; }
__device__ __forceinline__ unsigned short f2b(float f) {
  union { float f; unsigned u; } v; v.f = f;
  unsigned r = v.u + 0x7fffu + ((v.u >> 16) & 1u);  // round-to-nearest-even
  return (unsigned short)(r >> 16);
}
__device__ __forceinline__ float b2f(unsigned short u) {
  union { unsigned u; float f; } v; v.u = ((unsigned)u) << 16; return v.f;
}

// LDS tile layout with XOR swizzle: element (r,k) of a [rows]x128 bf16 tile lives at
// lofs(r,k). 16B chunks (8 ushorts) stay contiguous; chunk index ^= (r&15).
__device__ __forceinline__ int lofs(int r, int k) {
  return (r << 7) + ((((k >> 3) ^ r) & 15) << 3) + (k & 7);
}

// Single-wave LDS write->read sync: wave is lockstep (one PC); lgkmcnt(0) drain +
// compiler fence is sufficient for within-wave cross-lane exchange.
#define WAVE_SYNC() asm volatile("s_waitcnt lgkmcnt(0)" ::: "memory")

// Async global->LDS DMA, 16B per lane. LDS dest must be the WAVE-UNIFORM base;
// HW adds lane*16. Global src is per-lane. Drained by vmcnt (and by the
// vmcnt(0) the compiler emits before every s_barrier/__syncthreads).
__device__ __forceinline__ void gll16(const void* g, void* l) {
  __builtin_amdgcn_global_load_lds((const __attribute__((address_space(1))) void*)g,
                                   (__attribute__((address_space(3))) void*)l, 16, 0, 0);
}

// ---------------- CSR build ----------------

__global__ __launch_bounds__(256) void count_kernel(const int* __restrict__ dst,
                                                    int* __restrict__ cnt, int nE) {
  int e = blockIdx.x * 256 + threadIdx.x;
  if (e < nE) atomicAdd(&cnt[dst[e]], 1);
}

__global__ __launch_bounds__(1024) void scan1_kernel(int* __restrict__ cnt,
                                                     int* __restrict__ rowptr,
                                                     int* __restrict__ bsum,
                                                     float* __restrict__ dinv, int n) {
  __shared__ int wsum[16];
  const int tid = threadIdx.x;
  const int lane = tid & 63, wid = tid >> 6;
  int i = blockIdx.x * 1024 + tid;
  int v = (i < n) ? cnt[i] : 0;
  int x = v;
#pragma unroll
  for (int off = 1; off < 64; off <<= 1) {
    int y = __shfl_up(x, off, 64);
    if (lane >= off) x += y;
  }
  if (lane == 63) wsum[wid] = x;
  __syncthreads();
  if (tid == 0) {
    int s = 0;
#pragma unroll
    for (int w = 0; w < 16; ++w) { int t = wsum[w]; wsum[w] = s; s += t; }
    bsum[blockIdx.x] = s;
  }
  __syncthreads();
  if (i < n) {
    rowptr[i] = wsum[wid] + x - v;  // local exclusive
    dinv[i] = rsqrtf((float)v + 1.0f);
    cnt[i] = 0;
  }
}

__global__ __launch_bounds__(64) void scan2_kernel(int* __restrict__ bsum, int nb,
                                                   int* __restrict__ rowptr, int n, int E) {
  int lane = threadIdx.x;
  int v = (lane < nb) ? bsum[lane] : 0;
  int x = v;
#pragma unroll
  for (int off = 1; off < 64; off <<= 1) {
    int y = __shfl_up(x, off, 64);
    if (lane >= off) x += y;
  }
  if (lane < nb) bsum[lane] = x - v;  // exclusive
  if (lane == 0) rowptr[n] = E;
}

__global__ __launch_bounds__(1024) void scan3_kernel(int* __restrict__ rowptr,
                                                     const int* __restrict__ bsum, int n) {
  int i = blockIdx.x * 1024 + threadIdx.x;
  if (i < n) rowptr[i] += bsum[blockIdx.x];
}

// csr entry: .x = src node, .y = norm (float bits)
__global__ __launch_bounds__(256) void fill_kernel(const int* __restrict__ src,
                                                   const int* __restrict__ dst,
                                                   const int* __restrict__ rowptr,
                                                   int* __restrict__ cursor,
                                                   const float* __restrict__ dinv,
                                                   int2* __restrict__ csr, int nE) {
  int e = blockIdx.x * 256 + threadIdx.x;
  if (e >= nE) return;
  int d = dst[e], s = src[e];
  int pos = rowptr[d] + atomicAdd(&cursor[d], 1);
  int2 ent;
  ent.x = s;
  ent.y = __float_as_int(dinv[s] * dinv[d]);
  csr[pos] = ent;
}

// ---------------- weight pack: B-fragment order for mfma 16x16x32 ----------------
__global__ __launch_bounds__(256) void pack_kernel(const float* W0, const float* W1,
                                                   const float* W2, const float* W3,
                                                   const float* W4, const float* W5,
                                                   unsigned short* __restrict__ out) {
  const float* Ws[6] = {W0, W1, W2, W3, W4, W5};
  const float* W = Ws[blockIdx.y];
  int f = blockIdx.x * 256 + threadIdx.x;  // 0..16383
  int j = f & 7, L = (f >> 3) & 63, c = (f >> 9) & 7, t = f >> 12;
  int k = t * 32 + (L >> 4) * 8 + j;
  int n = c * 16 + (L & 15);
  out[(size_t)blockIdx.y * 16384 + f] = f2b(W[k * HH + n]);
}

// ---------------- shared device helpers ----------------

// 16-row MFMA stage; B-fragments from the block-shared LDS weight copy.
// Fragment f at bytes [f*1024 + lane*16] -> ds_read_b128, conflict-free
// (r7 measured SQ_LDS_BANK_CONFLICT = 0 with this pattern).
__device__ __forceinline__ void mfma_ldsW(const bf16x8 af[4],
                                          const unsigned short* __restrict__ Wl,
                                          int lane, f32x4 acc[8]) {
#pragma unroll
  for (int c = 0; c < 8; ++c) acc[c] = (f32x4){0.f, 0.f, 0.f, 0.f};
#pragma unroll
  for (int t = 0; t < 4; ++t) {
    bf16x8 wf[8];
#pragma unroll
    for (int c = 0; c < 8; ++c) wf[c] = *(const bf16x8*)&Wl[(t * 8 + c) * 512 + lane * 8];
#pragma unroll
    for (int c = 0; c < 8; ++c)
      acc[c] = __builtin_amdgcn_mfma_f32_16x16x32_bf16(af[t], wf[c], acc[c], 0, 0, 0);
  }
}

// A-fragments from a 16-row swizzled LDS tile (arow = lane&15).
__device__ __forceinline__ void lds_afrags16(const unsigned short* __restrict__ Tl,
                                             int m, int quad, bf16x8 af[4]) {
#pragma unroll
  for (int t = 0; t < 4; ++t)
    af[t] = *(const bf16x8*)&Tl[lofs(m, t * 32 + quad * 8)];
}

// ---------------- GEMM: A(fp32)[nrows,128] @ Wp -> bf16 out ----------------
// 4 waves/block, 16 rows/wave. Weights DMA'd once per block into 32KB LDS via
// global_load_lds (zero VGPR cost), A fragments from global fp32 in-register.
// __launch_bounds__(256,1): no VGPR cap (r7's missing ",1" capped at 128 -> spill).

__global__ __launch_bounds__(256, 1) void gemm_conv(const float* __restrict__ A,
                                                    const unsigned short* __restrict__ Wp,
                                                    unsigned short* __restrict__ out, int nrows) {
  __shared__ __align__(16) unsigned short Wl[16384];
  const int tid = threadIdx.x;
  const int lane = tid & 63, wave = tid >> 6;
  const int row0 = blockIdx.x * 64 + wave * 16;
  const int m = lane & 15, quad = lane >> 4;

  // async weight stage: 8 x 16B per lane, linear layout
#pragma unroll
  for (int i = 0; i < 8; ++i)
    gll16((const uint4*)Wp + i * 256 + tid, (uint4*)Wl + i * 256 + wave * 64);

  // A fragments straight from global fp32, converted in-register (hides DMA)
  const int gr = row0 + m;
  const bool rok = gr < nrows;
  const float* Arow = A + (size_t)gr * HH;
  bf16x8 af[4];
#pragma unroll
  for (int t = 0; t < 4; ++t) {
    const int k = t * 32 + quad * 8;
    float4 lo = make_float4(0.f, 0.f, 0.f, 0.f), hi = lo;
    if (rok) {
      lo = *(const float4*)(Arow + k);
      hi = *(const float4*)(Arow + k + 4);
    }
    union { ushort8v u; bf16x8 b; } cv;
    cv.u[0] = f2b(lo.x); cv.u[1] = f2b(lo.y); cv.u[2] = f2b(lo.z); cv.u[3] = f2b(lo.w);
    cv.u[4] = f2b(hi.x); cv.u[5] = f2b(hi.y); cv.u[6] = f2b(hi.z); cv.u[7] = f2b(hi.w);
    af[t] = cv.b;
  }

  __syncthreads();  // drains vmcnt (DMA done) -> weights visible to all waves

  f32x4 acc[8];
  mfma_ldsW(af, Wl, lane, acc);

#pragma unroll
  for (int c = 0; c < 8; ++c) {
    int col = c * 16 + m;
#pragma unroll
    for (int g = 0; g < 4; ++g) {
      int row = row0 + quad * 4 + g;
      if (row < nrows) out[(size_t)row * HH + col] = f2b(acc[c][g]);
    }
  }
}

// ---------------- agg: one wave per node ----------------
// out = leaky(sum norm*h[src] + self*dinv^2 + bias (+res fp32)); fp32 or bf16 out.

template <int RES, int OUTBF>
__global__ __launch_bounds__(256) void agg_kernel(const unsigned short* __restrict__ h,
                                                  const int* __restrict__ rowptr,
                                                  const int2* __restrict__ csr,
                                                  const float* __restrict__ dinv,
                                                  const float* __restrict__ bias,
                                                  const float* __restrict__ res,
                                                  void* __restrict__ outv, int n) {
  int node = blockIdx.x * 4 + (threadIdx.x >> 6);
  if (node >= n) return;
  int lane = threadIdx.x & 63;
  int c = lane << 1;
  int j = rowptr[node], end = rowptr[node + 1];
  float ax = 0.f, ay = 0.f;
  // 8-deep unroll: 8 outstanding gather loads per lane
  for (; j + 8 <= end; j += 8) {
    int2 e[8];
    ushort2 r[8];
#pragma unroll
    for (int q = 0; q < 8; ++q) e[q] = csr[j + q];
#pragma unroll
    for (int q = 0; q < 8; ++q) r[q] = *(const ushort2*)(h + (size_t)e[q].x * HH + c);
#pragma unroll
    for (int q = 0; q < 8; ++q) {
      float nv = __int_as_float(e[q].y);
      ax = fmaf(b2f(r[q].x), nv, ax); ay = fmaf(b2f(r[q].y), nv, ay);
    }
  }
  for (; j + 2 <= end; j += 2) {
    int2 e0 = csr[j], e1 = csr[j + 1];
    ushort2 r0 = *(const ushort2*)(h + (size_t)e0.x * HH + c);
    ushort2 r1 = *(const ushort2*)(h + (size_t)e1.x * HH + c);
    float n0 = __int_as_float(e0.y), n1 = __int_as_float(e1.y);
    ax = fmaf(b2f(r0.x), n0, ax); ay = fmaf(b2f(r0.y), n0, ay);
    ax = fmaf(b2f(r1.x), n1, ax); ay = fmaf(b2f(r1.y), n1, ay);
  }
  if (j < end) {
    int2 e0 = csr[j];
    float n0 = __int_as_float(e0.y);
    ushort2 r0 = *(const ushort2*)(h + (size_t)e0.x * HH + c);
    ax = fmaf(b2f(r0.x), n0, ax); ay = fmaf(b2f(r0.y), n0, ay);
  }
  float di = dinv[node], d2 = di * di;
  ushort2 hs = *(const ushort2*)(h + (size_t)node * HH + c);
  float2 b = *(const float2*)(bias + c);
  float ox = ax + b2f(hs.x) * d2 + b.x;
  float oy = ay + b2f(hs.y) * d2 + b.y;
  if (RES) {
    float2 r = *(const float2*)(res + (size_t)node * HH + c);
    ox += r.x; oy += r.y;
  }
  ox = lrelu(ox); oy = lrelu(oy);
  if (OUTBF) {
    ushort2 o; o.x = f2b(ox); o.y = f2b(oy);
    *(ushort2*)((unsigned short*)outv + (size_t)node * HH + c) = o;
  } else {
    *(float2*)((float*)outv + (size_t)node * HH + c) = make_float2(ox, oy);
  }
}

// ---------------- fusedMLP: 4-GEMM chain, shared W buffer + async DMA refill ----
// 4 waves/block, 16 rows/wave. ONE 32KB LDS weight buffer refilled per stage via
// global_load_lds (no VGPR round-trip — r7's pw[] spill source is gone). Each
// refill: issue DMA right after the buffer-free barrier, overlap with stage-pre
// LDS work, then a visibility barrier (whose implicit vmcnt(0) drains the DMA).
// Tiles wave-private (Ta/Tb 4KB each); gen via float4->bf16 regs parked in Tb;
// biases in BI. LDS total 72KB -> 2 blocks/CU (8 waves/CU).
// stage 1:  m  = leaky(f2@Wm1+bm1)                     Ta -> Tb
// stage 2:  h3 = leaky(m@Wm2+bm2 + f2); p=0.5*(h3+gen) Tb,Ta -> Ta
// stage 3:  q  = leaky(p@Wp1+bp1)                      Ta -> Tb
// stage 4:  out= leaky(q@Wp2+bp2)                      Tb -> fp32 global

__global__ __launch_bounds__(256, 1) void fusedMLP(const unsigned short* __restrict__ f2bf,
                                                   const unsigned short* __restrict__ Wm1p,
                                                   const unsigned short* __restrict__ Wm2p,
                                                   const unsigned short* __restrict__ Wp1p,
                                                   const unsigned short* __restrict__ Wp2p,
                                                   const float* __restrict__ bm1,
                                                   const float* __restrict__ bm2,
                                                   const float* __restrict__ bp1,
                                                   const float* __restrict__ bp2,
                                                   const float* __restrict__ gen,
                                                   float* __restrict__ out, int n) {
  __shared__ __align__(16) unsigned short Wl[16384];      // 32KB shared, refilled per stage
  __shared__ __align__(16) unsigned short Ta[4][16 * HH]; // 4 x 4KB wave tiles
  __shared__ __align__(16) unsigned short Tb[4][16 * HH]; // 4 x 4KB wave tiles
  __shared__ __align__(16) float Bi[4][4 * HH];           // 4 x 2KB biases
  const int tid = threadIdx.x;
  const int lane = tid & 63, wave = tid >> 6;
  const int row0 = blockIdx.x * 64 + wave * 16;
  const int m = lane & 15, quad = lane >> 4;
  unsigned short* TA = Ta[wave];
  unsigned short* TB = Tb[wave];
  float* BI = Bi[wave];

  // --- issue W1 DMA first (async; hides under the staging below) ---
#pragma unroll
  for (int i = 0; i < 8; ++i)
    gll16((const uint4*)Wm1p + i * 256 + tid, (uint4*)Wl + i * 256 + wave * 64);

  // --- f2 tile -> TA (swizzled), 4 x 16B per lane ---
#pragma unroll
  for (int i = 0; i < 4; ++i) {
    int idx = i * 64 + lane;            // 16B-chunk id 0..255
    int r = idx >> 4, k = (idx & 15) << 3;
    int gr = row0 + r;
    ushort8v v = {0, 0, 0, 0, 0, 0, 0, 0};
    if (gr < n) v = *(const ushort8v*)(f2bf + (size_t)gr * HH + k);
    *(ushort8v*)&TA[lofs(r, k)] = v;
  }

  // --- gen -> bf16 regs in staging-chunk layout (held until stage 2) ---
  ushort4 genb[8];
#pragma unroll
  for (int i = 0; i < 8; ++i) {
    int idx = i * 64 + lane;            // float4-chunk id 0..511
    int r = idx >> 5, c4 = (idx & 31) << 2;
    int gr = row0 + r;
    float4 v = make_float4(0.f, 0.f, 0.f, 0.f);
    if (gr < n) v = *(const float4*)(gen + (size_t)gr * HH + c4);
    genb[i].x = f2b(v.x); genb[i].y = f2b(v.y); genb[i].z = f2b(v.z); genb[i].w = f2b(v.w);
  }

  // --- all 4 biases -> BI, 2 x float4 per lane; layout [mat*128 + col] ---
  {
    const float* b01 = (lane < 32) ? bm1 : bm2;
    const float* b23 = (lane < 32) ? bp1 : bp2;
    int col = (lane & 31) << 2;
    float4 v0 = *(const float4*)(b01 + col);
    float4 v1 = *(const float4*)(b23 + col);
    *(float4*)&BI[lane * 4] = v0;         // lane<32 -> bm1, else bm2
    *(float4*)&BI[256 + lane * 4] = v1;   // lane<32 -> bp1, else bp2
  }

  __syncthreads();  // B1: vmcnt(0)+lgkm drain -> W1, TA, BI visible

  bf16x8 af[4];
  f32x4 acc[8];
  float bv[8];

  // ---- stage 1: m = leaky(f2@Wm1+bm1), Ta -> Tb ----
#pragma unroll
  for (int cc = 0; cc < 8; ++cc) bv[cc] = BI[cc * 16 + m];
  lds_afrags16(TA, m, quad, af);
  mfma_ldsW(af, Wl, lane, acc);
#pragma unroll
  for (int cc = 0; cc < 8; ++cc) {
    int col = cc * 16 + m;
#pragma unroll
    for (int g = 0; g < 4; ++g)
      TB[lofs(quad * 4 + g, col)] = f2b(lrelu(acc[cc][g] + bv[cc]));
  }
  __syncthreads();  // B2: all waves done reading W1

  // refill W2 (async) + stage-2 pre-work overlaps the DMA
#pragma unroll
  for (int i = 0; i < 8; ++i)
    gll16((const uint4*)Wm2p + i * 256 + tid, (uint4*)Wl + i * 256 + wave * 64);
#pragma unroll
  for (int cc = 0; cc < 8; ++cc) bv[cc] = BI[128 + cc * 16 + m];
  lds_afrags16(TB, m, quad, af);  // consume m into regs
  WAVE_SYNC();                    // af loaded before TB is overwritten
  // park gen (regs) into TB, staging layout
#pragma unroll
  for (int i = 0; i < 8; ++i) {
    int idx = i * 64 + lane;
    int r = idx >> 5, c4 = (idx & 31) << 2;
    *(ushort4*)&TB[lofs(r, c4)] = genb[i];
  }
  __syncthreads();  // B3: W2 visible (vmcnt drained); gen parks visible

  // ---- stage 2: h3 = leaky(m@Wm2+bm2+f2); p = 0.5*(h3+gen), Tb,Ta -> Ta ----
  mfma_ldsW(af, Wl, lane, acc);
#pragma unroll
  for (int cc = 0; cc < 8; ++cc) {
    int col = cc * 16 + m;
#pragma unroll
    for (int g = 0; g < 4; ++g) {
      int lr = quad * 4 + g;
      float f2v = b2f(TA[lofs(lr, col)]);   // residual (same-lane slot)
      float v = lrelu(acc[cc][g] + bv[cc] + f2v);
      float gv = b2f(TB[lofs(lr, col)]);    // gen parked in TB
      TA[lofs(lr, col)] = f2b(0.5f * (v + gv));
    }
  }
  __syncthreads();  // B4: all waves done reading W2

  // refill W3 (async) + stage-3 pre-work
#pragma unroll
  for (int i = 0; i < 8; ++i)
    gll16((const uint4*)Wp1p + i * 256 + tid, (uint4*)Wl + i * 256 + wave * 64);
#pragma unroll
  for (int cc = 0; cc < 8; ++cc) bv[cc] = BI[256 + cc * 16 + m];
  lds_afrags16(TA, m, quad, af);  // p values (epi-2 writes drained at B4)
  __syncthreads();  // B5: W3 visible

  // ---- stage 3: q = leaky(p@Wp1+bp1), Ta -> Tb ----
  mfma_ldsW(af, Wl, lane, acc);
#pragma unroll
  for (int cc = 0; cc < 8; ++cc) {
    int col = cc * 16 + m;
#pragma unroll
    for (int g = 0; g < 4; ++g)
      TB[lofs(quad * 4 + g, col)] = f2b(lrelu(acc[cc][g] + bv[cc]));
  }
  __syncthreads();  // B6: all waves done reading W3

  // refill W4 (async) + stage-4 pre-work
#pragma unroll
  for (int i = 0; i < 8; ++i)
    gll16((const uint4*)Wp2p + i * 256 + tid, (uint4*)Wl + i * 256 + wave * 64);
#pragma unroll
  for (int cc = 0; cc < 8; ++cc) bv[cc] = BI[384 + cc * 16 + m];
  lds_afrags16(TB, m, quad, af);  // q values (epi-3 writes drained at B6)
  __syncthreads();  // B7: W4 visible

  // ---- stage 4: out = leaky(q@Wp2+bp2), Tb -> global fp32 ----
  mfma_ldsW(af, Wl, lane, acc);
#pragma unroll
  for (int cc = 0; cc < 8; ++cc) {
    int col = cc * 16 + m;
#pragma unroll
    for (int g = 0; g < 4; ++g) {
      int row = row0 + quad * 4 + g;
      if (row < n) out[(size_t)row * HH + col] = lrelu(acc[cc][g] + bv[cc]);
    }
  }
}

// ---------------- launcher ----------------

extern "C" void kernel_launch(void* const* d_in, const int* in_sizes, int n_in,
                              void* d_out, int out_size, void* d_ws, size_t ws_size,
                              hipStream_t stream) {
  const float* x   = (const float*)d_in[0];
  const int* ei    = (const int*)d_in[1];
  const float* gen = (const float*)d_in[2];
  const float* Wc1 = (const float*)d_in[3];
  const float* bc1 = (const float*)d_in[4];
  const float* Wc2 = (const float*)d_in[5];
  const float* bc2 = (const float*)d_in[6];
  const float* Wm1 = (const float*)d_in[7];
  const float* bm1 = (const float*)d_in[8];
  const float* Wm2 = (const float*)d_in[9];
  const float* bm2 = (const float*)d_in[10];
  const float* Wp1 = (const float*)d_in[11];
  const float* bp1 = (const float*)d_in[12];
  const float* Wp2 = (const float*)d_in[13];
  const float* bp2 = (const float*)d_in[14];

  const int N = in_sizes[0] / HH;
  const int E = in_sizes[1] / 2;
  const int* src = ei;
  const int* dst = ei + E;

  char* ws = (char*)d_ws;
  size_t off = 0;
  auto alloc = [&](size_t bytes) { void* p = ws + off; off += (bytes + 255) & ~(size_t)255; return p; };
  float* dinv            = (float*)alloc((size_t)N * 4);
  int*   rowptr          = (int*)  alloc((size_t)(N + 1) * 4);
  int*   cursor          = (int*)  alloc((size_t)N * 4);
  int*   bsum            = (int*)  alloc((size_t)64 * 4);
  int2*  csr             = (int2*) alloc((size_t)E * 8);
  unsigned short* h_bf   = (unsigned short*)alloc((size_t)N * HH * 2);
  unsigned short* t2_bf  = (unsigned short*)alloc((size_t)N * HH * 2);
  unsigned short* f2_bf  = (unsigned short*)alloc((size_t)N * HH * 2);
  float* f1_f32          = (float*)alloc((size_t)N * HH * 4);
  unsigned short* packed = (unsigned short*)alloc((size_t)6 * 16384 * 2);
  float* fOut = (float*)d_out;

  const int cblocks = (N + 63) / 64;      // 4 waves x 16 rows per 256-thr block
  const int eblocks = (E + 255) / 256;
  const int ablocks = (N + 3) / 4;
  const int sblocks = (N + 1023) / 1024;  // <= 64 for N <= 65536

  // weight packing
  pack_kernel<<<dim3(64, 6), 256, 0, stream>>>(Wc1, Wc2, Wm1, Wm2, Wp1, Wp2, packed);

  // CSR build
  hipMemsetAsync(cursor, 0, (size_t)N * 4, stream);
  count_kernel<<<eblocks, 256, 0, stream>>>(dst, cursor, E);
  scan1_kernel<<<sblocks, 1024, 0, stream>>>(cursor, rowptr, bsum, dinv, N);
  scan2_kernel<<<1, 64, 0, stream>>>(bsum, sblocks, rowptr, N, E);
  scan3_kernel<<<sblocks, 1024, 0, stream>>>(rowptr, bsum, N);
  fill_kernel<<<eblocks, 256, 0, stream>>>(src, dst, rowptr, cursor, dinv, csr, E);

  // conv1: h_bf = bf16(x @ Wc1)
  gemm_conv<<<cblocks, 256, 0, stream>>>(x, packed + 0 * 16384, h_bf, N);
  // agg1: f1 = leaky(agg(h_bf)+self+bc1)  [fp32]
  agg_kernel<0, 0><<<ablocks, 256, 0, stream>>>(h_bf, rowptr, csr, dinv, bc1, nullptr, f1_f32, N);
  // conv2: t2 = bf16(f1 @ Wc2)
  gemm_conv<<<cblocks, 256, 0, stream>>>(f1_f32, packed + 1 * 16384, t2_bf, N);
  // agg2: f2 = leaky(agg(t2)+self+bc2+f1)  [bf16 — only consumed as bf16]
  agg_kernel<1, 1><<<ablocks, 256, 0, stream>>>(t2_bf, rowptr, csr, dinv, bc2, f1_f32, f2_bf, N);
  // fusedMLP: MLP + interp + proj -> d_out
  fusedMLP<<<cblocks, 256, 0, stream>>>(f2_bf,
                                        packed + 2 * 16384, packed + 3 * 16384,
                                        packed + 4 * 16384, packed + 5 * 16384,
                                        bm1, bm2, bp1, bp2, gen, fOut, N);
}

// Round 9
// 277.456 us; speedup vs baseline: 1.1347x; 1.0500x over previous
//
#include <hip/hip_runtime.h>
#include <cstdint>
#include <cstddef>

#define HH 128
#define SLOPE 0.01f

typedef __attribute__((ext_vector_type(8))) __bf16 bf16x8;
typedef __attribute__((ext_vector_type(8))) unsigned short ushort8v;
typedef __attribute__((ext_vector_type(4))) float f32x4;

__device__ __forceinline__ float lrelu(float x) { return x >= 0.f ? x : SLOPE * x; }
__device__ __forceinline__ unsigned short f2b(float f) {
  union { float f; unsigned u; } v; v.f = f;
  unsigned r = v.u + 0x7fffu + ((v.u >> 16) & 1u);  // round-to-nearest-even
  return (unsigned short)(r >> 16);
}
__device__ __forceinline__ float b2f(unsigned short u) {
  union { unsigned u; float f; } v; v.u = ((unsigned)u) << 16; return v.f;
}

// LDS tile layout with XOR swizzle: element (r,k) of a [rows]x128 bf16 tile lives at
// lofs(r,k). 16B chunks (8 ushorts) stay contiguous; chunk index ^= (r&15).
__device__ __forceinline__ int lofs(int r, int k) {
  return (r << 7) + ((((k >> 3) ^ r) & 15) << 3) + (k & 7);
}

// Single-wave LDS write->read sync: wave is lockstep (one PC); lgkmcnt(0) drain +
// compiler fence is sufficient for within-wave cross-lane exchange.
#define WAVE_SYNC() asm volatile("s_waitcnt lgkmcnt(0)" ::: "memory")

// Async global->LDS DMA, 16B per lane. LDS dest must be the WAVE-UNIFORM base;
// HW adds lane*16. Global src is per-lane. Drained by the vmcnt(0) the compiler
// emits before every s_barrier/__syncthreads.
__device__ __forceinline__ void gll16(const void* g, void* l) {
  __builtin_amdgcn_global_load_lds((const __attribute__((address_space(1))) void*)g,
                                   (__attribute__((address_space(3))) void*)l, 16, 0, 0);
}

// ---------------- CSR build ----------------

// count + rank: atomicAdd's return value is this edge's within-node rank.
// Storing it lets fill_kernel run atomic-free.
__global__ __launch_bounds__(256) void count_kernel(const int* __restrict__ dst,
                                                    int* __restrict__ cnt,
                                                    int* __restrict__ rank, int nE) {
  int e = blockIdx.x * 256 + threadIdx.x;
  if (e < nE) rank[e] = atomicAdd(&cnt[dst[e]], 1);
}

__global__ __launch_bounds__(1024) void scan1_kernel(int* __restrict__ cnt,
                                                     int* __restrict__ rowptr,
                                                     int* __restrict__ bsum,
                                                     float* __restrict__ dinv, int n) {
  __shared__ int wsum[16];
  const int tid = threadIdx.x;
  const int lane = tid & 63, wid = tid >> 6;
  int i = blockIdx.x * 1024 + tid;
  int v = (i < n) ? cnt[i] : 0;
  int x = v;
#pragma unroll
  for (int off = 1; off < 64; off <<= 1) {
    int y = __shfl_up(x, off, 64);
    if (lane >= off) x += y;
  }
  if (lane == 63) wsum[wid] = x;
  __syncthreads();
  if (tid == 0) {
    int s = 0;
#pragma unroll
    for (int w = 0; w < 16; ++w) { int t = wsum[w]; wsum[w] = s; s += t; }
    bsum[blockIdx.x] = s;
  }
  __syncthreads();
  if (i < n) {
    rowptr[i] = wsum[wid] + x - v;  // local exclusive
    dinv[i] = rsqrtf((float)v + 1.0f);
  }
}

__global__ __launch_bounds__(64) void scan2_kernel(int* __restrict__ bsum, int nb,
                                                   int* __restrict__ rowptr, int n, int E) {
  int lane = threadIdx.x;
  int v = (lane < nb) ? bsum[lane] : 0;
  int x = v;
#pragma unroll
  for (int off = 1; off < 64; off <<= 1) {
    int y = __shfl_up(x, off, 64);
    if (lane >= off) x += y;
  }
  if (lane < nb) bsum[lane] = x - v;  // exclusive
  if (lane == 0) rowptr[n] = E;
}

__global__ __launch_bounds__(1024) void scan3_kernel(int* __restrict__ rowptr,
                                                     const int* __restrict__ bsum, int n) {
  int i = blockIdx.x * 1024 + threadIdx.x;
  if (i < n) rowptr[i] += bsum[blockIdx.x];
}

// csr entry: .x = src node, .y = norm (float bits). Atomic-free (rank-based).
__global__ __launch_bounds__(256) void fill_kernel(const int* __restrict__ src,
                                                   const int* __restrict__ dst,
                                                   const int* __restrict__ rowptr,
                                                   const int* __restrict__ rank,
                                                   const float* __restrict__ dinv,
                                                   int2* __restrict__ csr, int nE) {
  int e = blockIdx.x * 256 + threadIdx.x;
  if (e >= nE) return;
  int d = dst[e], s = src[e];
  int pos = rowptr[d] + rank[e];
  int2 ent;
  ent.x = s;
  ent.y = __float_as_int(dinv[s] * dinv[d]);
  csr[pos] = ent;
}

// ---------------- weight pack: B-fragment order for mfma 16x16x32 ----------------
__global__ __launch_bounds__(256) void pack_kernel(const float* W0, const float* W1,
                                                   const float* W2, const float* W3,
                                                   const float* W4, const float* W5,
                                                   unsigned short* __restrict__ out) {
  const float* Ws[6] = {W0, W1, W2, W3, W4, W5};
  const float* W = Ws[blockIdx.y];
  int f = blockIdx.x * 256 + threadIdx.x;  // 0..16383
  int j = f & 7, L = (f >> 3) & 63, c = (f >> 9) & 7, t = f >> 12;
  int k = t * 32 + (L >> 4) * 8 + j;
  int n = c * 16 + (L & 15);
  out[(size_t)blockIdx.y * 16384 + f] = f2b(W[k * HH + n]);
}

// ---------------- shared device helpers ----------------

// 16-row MFMA stage; B-fragments from the block-shared LDS weight copy.
// Fragment f at bytes [f*1024 + lane*16] -> ds_read_b128, conflict-free.
__device__ __forceinline__ void mfma_ldsW(const bf16x8 af[4],
                                          const unsigned short* __restrict__ Wl,
                                          int lane, f32x4 acc[8]) {
#pragma unroll
  for (int c = 0; c < 8; ++c) acc[c] = (f32x4){0.f, 0.f, 0.f, 0.f};
#pragma unroll
  for (int t = 0; t < 4; ++t) {
    bf16x8 wf[8];
#pragma unroll
    for (int c = 0; c < 8; ++c) wf[c] = *(const bf16x8*)&Wl[(t * 8 + c) * 512 + lane * 8];
#pragma unroll
    for (int c = 0; c < 8; ++c)
      acc[c] = __builtin_amdgcn_mfma_f32_16x16x32_bf16(af[t], wf[c], acc[c], 0, 0, 0);
  }
}

// A-fragments from a 16-row swizzled LDS tile (arow = lane&15).
__device__ __forceinline__ void lds_afrags16(const unsigned short* __restrict__ Tl,
                                             int m, int quad, bf16x8 af[4]) {
#pragma unroll
  for (int t = 0; t < 4; ++t)
    af[t] = *(const bf16x8*)&Tl[lofs(m, t * 32 + quad * 8)];
}

// ---------------- GEMM: A(fp32)[nrows,128] @ Wp -> bf16 out ----------------
// 4 waves/block, 16 rows/wave. Weights DMA'd once per block into 32KB LDS via
// global_load_lds (zero VGPR cost). r8-verified.

__global__ __launch_bounds__(256, 1) void gemm_conv(const float* __restrict__ A,
                                                    const unsigned short* __restrict__ Wp,
                                                    unsigned short* __restrict__ out, int nrows) {
  __shared__ __align__(16) unsigned short Wl[16384];
  const int tid = threadIdx.x;
  const int lane = tid & 63, wave = tid >> 6;
  const int row0 = blockIdx.x * 64 + wave * 16;
  const int m = lane & 15, quad = lane >> 4;

  // async weight stage: 8 x 16B per lane, linear layout
#pragma unroll
  for (int i = 0; i < 8; ++i)
    gll16((const uint4*)Wp + i * 256 + tid, (uint4*)Wl + i * 256 + wave * 64);

  // A fragments straight from global fp32, converted in-register (hides DMA)
  const int gr = row0 + m;
  const bool rok = gr < nrows;
  const float* Arow = A + (size_t)gr * HH;
  bf16x8 af[4];
#pragma unroll
  for (int t = 0; t < 4; ++t) {
    const int k = t * 32 + quad * 8;
    float4 lo = make_float4(0.f, 0.f, 0.f, 0.f), hi = lo;
    if (rok) {
      lo = *(const float4*)(Arow + k);
      hi = *(const float4*)(Arow + k + 4);
    }
    union { ushort8v u; bf16x8 b; } cv;
    cv.u[0] = f2b(lo.x); cv.u[1] = f2b(lo.y); cv.u[2] = f2b(lo.z); cv.u[3] = f2b(lo.w);
    cv.u[4] = f2b(hi.x); cv.u[5] = f2b(hi.y); cv.u[6] = f2b(hi.z); cv.u[7] = f2b(hi.w);
    af[t] = cv.b;
  }

  __syncthreads();  // drains vmcnt (DMA done) -> weights visible to all waves

  f32x4 acc[8];
  mfma_ldsW(af, Wl, lane, acc);

#pragma unroll
  for (int c = 0; c < 8; ++c) {
    int col = c * 16 + m;
#pragma unroll
    for (int g = 0; g < 4; ++g) {
      int row = row0 + quad * 4 + g;
      if (row < nrows) out[(size_t)row * HH + col] = f2b(acc[c][g]);
    }
  }
}

// ---------------- agg: one wave per node, 2 edges in flight per step ----------------
// Half-wave h (lane>>5) owns edge parity h; each lane gathers ushort4 (4 cols).
// Halves the gather instruction count vs ushort2/whole-wave and doubles rows in
// flight. Final cross-half combine via shfl_xor(32); epilogue on lanes 0-31 with
// 16B accesses. fp32 sum order differs from r8 (already nondeterministic via
// cursor/rank races; tolerance absorbs it).

template <int RES, int OUTBF>
__global__ __launch_bounds__(256) void agg_kernel(const unsigned short* __restrict__ h,
                                                  const int* __restrict__ rowptr,
                                                  const int2* __restrict__ csr,
                                                  const float* __restrict__ dinv,
                                                  const float* __restrict__ bias,
                                                  const float* __restrict__ res,
                                                  void* __restrict__ outv, int n) {
  int node = blockIdx.x * 4 + (threadIdx.x >> 6);
  if (node >= n) return;
  const int lane = threadIdx.x & 63;
  const int p = lane >> 5;          // edge parity this half-wave handles
  const int c4 = (lane & 31) << 2;  // 4 columns per lane
  int j = rowptr[node];
  const int end = rowptr[node + 1];
  float a0 = 0.f, a1 = 0.f, a2 = 0.f, a3 = 0.f;

  // 8 edges per iteration (4 per half-wave), 4 ushort4 gathers in flight/lane
  for (; j + 8 <= end; j += 8) {
    int2 e[4];
    ushort4 r[4];
#pragma unroll
    for (int q = 0; q < 4; ++q) e[q] = csr[j + 2 * q + p];
#pragma unroll
    for (int q = 0; q < 4; ++q) r[q] = *(const ushort4*)(h + (size_t)e[q].x * HH + c4);
#pragma unroll
    for (int q = 0; q < 4; ++q) {
      float nv = __int_as_float(e[q].y);
      a0 = fmaf(b2f(r[q].x), nv, a0); a1 = fmaf(b2f(r[q].y), nv, a1);
      a2 = fmaf(b2f(r[q].z), nv, a2); a3 = fmaf(b2f(r[q].w), nv, a3);
    }
  }
  // 2 edges per iteration
  for (; j + 2 <= end; j += 2) {
    int2 e = csr[j + p];
    ushort4 r = *(const ushort4*)(h + (size_t)e.x * HH + c4);
    float nv = __int_as_float(e.y);
    a0 = fmaf(b2f(r.x), nv, a0); a1 = fmaf(b2f(r.y), nv, a1);
    a2 = fmaf(b2f(r.z), nv, a2); a3 = fmaf(b2f(r.w), nv, a3);
  }
  // odd tail: parity-0 half only
  if (j < end && p == 0) {
    int2 e = csr[j];
    ushort4 r = *(const ushort4*)(h + (size_t)e.x * HH + c4);
    float nv = __int_as_float(e.y);
    a0 = fmaf(b2f(r.x), nv, a0); a1 = fmaf(b2f(r.y), nv, a1);
    a2 = fmaf(b2f(r.z), nv, a2); a3 = fmaf(b2f(r.w), nv, a3);
  }

  // combine the two edge-parity halves (lane L <-> lane L^32, same columns)
  a0 += __shfl_xor(a0, 32);
  a1 += __shfl_xor(a1, 32);
  a2 += __shfl_xor(a2, 32);
  a3 += __shfl_xor(a3, 32);

  if (p == 0) {  // lanes 0-31: epilogue + store (16B accesses)
    float di = dinv[node], d2 = di * di;
    ushort4 hs = *(const ushort4*)(h + (size_t)node * HH + c4);
    float4 b = *(const float4*)(bias + c4);
    float o0 = a0 + b2f(hs.x) * d2 + b.x;
    float o1 = a1 + b2f(hs.y) * d2 + b.y;
    float o2 = a2 + b2f(hs.z) * d2 + b.z;
    float o3 = a3 + b2f(hs.w) * d2 + b.w;
    if (RES) {
      float4 r = *(const float4*)(res + (size_t)node * HH + c4);
      o0 += r.x; o1 += r.y; o2 += r.z; o3 += r.w;
    }
    o0 = lrelu(o0); o1 = lrelu(o1); o2 = lrelu(o2); o3 = lrelu(o3);
    if (OUTBF) {
      ushort4 o;
      o.x = f2b(o0); o.y = f2b(o1); o.z = f2b(o2); o.w = f2b(o3);
      *(ushort4*)((unsigned short*)outv + (size_t)node * HH + c4) = o;
    } else {
      *(float4*)((float*)outv + (size_t)node * HH + c4) = make_float4(o0, o1, o2, o3);
    }
  }
}

// ---------------- fusedMLP: 4-GEMM chain, shared W buffer + async DMA refill ----
// r8-verified: 4 waves/block, 16 rows/wave, one 32KB W buffer DMA-refilled per
// stage, wave-private Ta/Tb tiles, gen parked in Tb, biases in BI. LDS 72KB.

__global__ __launch_bounds__(256, 1) void fusedMLP(const unsigned short* __restrict__ f2bf,
                                                   const unsigned short* __restrict__ Wm1p,
                                                   const unsigned short* __restrict__ Wm2p,
                                                   const unsigned short* __restrict__ Wp1p,
                                                   const unsigned short* __restrict__ Wp2p,
                                                   const float* __restrict__ bm1,
                                                   const float* __restrict__ bm2,
                                                   const float* __restrict__ bp1,
                                                   const float* __restrict__ bp2,
                                                   const float* __restrict__ gen,
                                                   float* __restrict__ out, int n) {
  __shared__ __align__(16) unsigned short Wl[16384];      // 32KB shared, refilled per stage
  __shared__ __align__(16) unsigned short Ta[4][16 * HH]; // 4 x 4KB wave tiles
  __shared__ __align__(16) unsigned short Tb[4][16 * HH]; // 4 x 4KB wave tiles
  __shared__ __align__(16) float Bi[4][4 * HH];           // 4 x 2KB biases
  const int tid = threadIdx.x;
  const int lane = tid & 63, wave = tid >> 6;
  const int row0 = blockIdx.x * 64 + wave * 16;
  const int m = lane & 15, quad = lane >> 4;
  unsigned short* TA = Ta[wave];
  unsigned short* TB = Tb[wave];
  float* BI = Bi[wave];

  // --- issue W1 DMA first (async; hides under the staging below) ---
#pragma unroll
  for (int i = 0; i < 8; ++i)
    gll16((const uint4*)Wm1p + i * 256 + tid, (uint4*)Wl + i * 256 + wave * 64);

  // --- f2 tile -> TA (swizzled), 4 x 16B per lane ---
#pragma unroll
  for (int i = 0; i < 4; ++i) {
    int idx = i * 64 + lane;            // 16B-chunk id 0..255
    int r = idx >> 4, k = (idx & 15) << 3;
    int gr = row0 + r;
    ushort8v v = {0, 0, 0, 0, 0, 0, 0, 0};
    if (gr < n) v = *(const ushort8v*)(f2bf + (size_t)gr * HH + k);
    *(ushort8v*)&TA[lofs(r, k)] = v;
  }

  // --- gen -> bf16 regs in staging-chunk layout (held until stage 2) ---
  ushort4 genb[8];
#pragma unroll
  for (int i = 0; i < 8; ++i) {
    int idx = i * 64 + lane;            // float4-chunk id 0..511
    int r = idx >> 5, c4 = (idx & 31) << 2;
    int gr = row0 + r;
    float4 v = make_float4(0.f, 0.f, 0.f, 0.f);
    if (gr < n) v = *(const float4*)(gen + (size_t)gr * HH + c4);
    genb[i].x = f2b(v.x); genb[i].y = f2b(v.y); genb[i].z = f2b(v.z); genb[i].w = f2b(v.w);
  }

  // --- all 4 biases -> BI, 2 x float4 per lane; layout [mat*128 + col] ---
  {
    const float* b01 = (lane < 32) ? bm1 : bm2;
    const float* b23 = (lane < 32) ? bp1 : bp2;
    int col = (lane & 31) << 2;
    float4 v0 = *(const float4*)(b01 + col);
    float4 v1 = *(const float4*)(b23 + col);
    *(float4*)&BI[lane * 4] = v0;         // lane<32 -> bm1, else bm2
    *(float4*)&BI[256 + lane * 4] = v1;   // lane<32 -> bp1, else bp2
  }

  __syncthreads();  // B1: vmcnt(0)+lgkm drain -> W1, TA, BI visible

  bf16x8 af[4];
  f32x4 acc[8];
  float bv[8];

  // ---- stage 1: m = leaky(f2@Wm1+bm1), Ta -> Tb ----
#pragma unroll
  for (int cc = 0; cc < 8; ++cc) bv[cc] = BI[cc * 16 + m];
  lds_afrags16(TA, m, quad, af);
  mfma_ldsW(af, Wl, lane, acc);
#pragma unroll
  for (int cc = 0; cc < 8; ++cc) {
    int col = cc * 16 + m;
#pragma unroll
    for (int g = 0; g < 4; ++g)
      TB[lofs(quad * 4 + g, col)] = f2b(lrelu(acc[cc][g] + bv[cc]));
  }
  __syncthreads();  // B2: all waves done reading W1

  // refill W2 (async) + stage-2 pre-work overlaps the DMA
#pragma unroll
  for (int i = 0; i < 8; ++i)
    gll16((const uint4*)Wm2p + i * 256 + tid, (uint4*)Wl + i * 256 + wave * 64);
#pragma unroll
  for (int cc = 0; cc < 8; ++cc) bv[cc] = BI[128 + cc * 16 + m];
  lds_afrags16(TB, m, quad, af);  // consume m into regs
  WAVE_SYNC();                    // af loaded before TB is overwritten
  // park gen (regs) into TB, staging layout
#pragma unroll
  for (int i = 0; i < 8; ++i) {
    int idx = i * 64 + lane;
    int r = idx >> 5, c4 = (idx & 31) << 2;
    *(ushort4*)&TB[lofs(r, c4)] = genb[i];
  }
  __syncthreads();  // B3: W2 visible (vmcnt drained); gen parks visible

  // ---- stage 2: h3 = leaky(m@Wm2+bm2+f2); p = 0.5*(h3+gen), Tb,Ta -> Ta ----
  mfma_ldsW(af, Wl, lane, acc);
#pragma unroll
  for (int cc = 0; cc < 8; ++cc) {
    int col = cc * 16 + m;
#pragma unroll
    for (int g = 0; g < 4; ++g) {
      int lr = quad * 4 + g;
      float f2v = b2f(TA[lofs(lr, col)]);   // residual (same-lane slot)
      float v = lrelu(acc[cc][g] + bv[cc] + f2v);
      float gv = b2f(TB[lofs(lr, col)]);    // gen parked in TB
      TA[lofs(lr, col)] = f2b(0.5f * (v + gv));
    }
  }
  __syncthreads();  // B4: all waves done reading W2

  // refill W3 (async) + stage-3 pre-work
#pragma unroll
  for (int i = 0; i < 8; ++i)
    gll16((const uint4*)Wp1p + i * 256 + tid, (uint4*)Wl + i * 256 + wave * 64);
#pragma unroll
  for (int cc = 0; cc < 8; ++cc) bv[cc] = BI[256 + cc * 16 + m];
  lds_afrags16(TA, m, quad, af);  // p values (epi-2 writes drained at B4)
  __syncthreads();  // B5: W3 visible

  // ---- stage 3: q = leaky(p@Wp1+bp1), Ta -> Tb ----
  mfma_ldsW(af, Wl, lane, acc);
#pragma unroll
  for (int cc = 0; cc < 8; ++cc) {
    int col = cc * 16 + m;
#pragma unroll
    for (int g = 0; g < 4; ++g)
      TB[lofs(quad * 4 + g, col)] = f2b(lrelu(acc[cc][g] + bv[cc]));
  }
  __syncthreads();  // B6: all waves done reading W3

  // refill W4 (async) + stage-4 pre-work
#pragma unroll
  for (int i = 0; i < 8; ++i)
    gll16((const uint4*)Wp2p + i * 256 + tid, (uint4*)Wl + i * 256 + wave * 64);
#pragma unroll
  for (int cc = 0; cc < 8; ++cc) bv[cc] = BI[384 + cc * 16 + m];
  lds_afrags16(TB, m, quad, af);  // q values (epi-3 writes drained at B6)
  __syncthreads();  // B7: W4 visible

  // ---- stage 4: out = leaky(q@Wp2+bp2), Tb -> global fp32 ----
  mfma_ldsW(af, Wl, lane, acc);
#pragma unroll
  for (int cc = 0; cc < 8; ++cc) {
    int col = cc * 16 + m;
#pragma unroll
    for (int g = 0; g < 4; ++g) {
      int row = row0 + quad * 4 + g;
      if (row < n) out[(size_t)row * HH + col] = lrelu(acc[cc][g] + bv[cc]);
    }
  }
}

// ---------------- launcher ----------------

extern "C" void kernel_launch(void* const* d_in, const int* in_sizes, int n_in,
                              void* d_out, int out_size, void* d_ws, size_t ws_size,
                              hipStream_t stream) {
  const float* x   = (const float*)d_in[0];
  const int* ei    = (const int*)d_in[1];
  const float* gen = (const float*)d_in[2];
  const float* Wc1 = (const float*)d_in[3];
  const float* bc1 = (const float*)d_in[4];
  const float* Wc2 = (const float*)d_in[5];
  const float* bc2 = (const float*)d_in[6];
  const float* Wm1 = (const float*)d_in[7];
  const float* bm1 = (const float*)d_in[8];
  const float* Wm2 = (const float*)d_in[9];
  const float* bm2 = (const float*)d_in[10];
  const float* Wp1 = (const float*)d_in[11];
  const float* bp1 = (const float*)d_in[12];
  const float* Wp2 = (const float*)d_in[13];
  const float* bp2 = (const float*)d_in[14];

  const int N = in_sizes[0] / HH;
  const int E = in_sizes[1] / 2;
  const int* src = ei;
  const int* dst = ei + E;

  char* ws = (char*)d_ws;
  size_t off = 0;
  auto alloc = [&](size_t bytes) { void* p = ws + off; off += (bytes + 255) & ~(size_t)255; return p; };
  float* dinv            = (float*)alloc((size_t)N * 4);
  int*   rowptr          = (int*)  alloc((size_t)(N + 1) * 4);
  int*   cnt             = (int*)  alloc((size_t)N * 4);
  int*   bsum            = (int*)  alloc((size_t)64 * 4);
  int*   rank            = (int*)  alloc((size_t)E * 4);
  int2*  csr             = (int2*) alloc((size_t)E * 8);
  unsigned short* h_bf   = (unsigned short*)alloc((size_t)N * HH * 2);
  unsigned short* t2_bf  = (unsigned short*)alloc((size_t)N * HH * 2);
  unsigned short* f2_bf  = (unsigned short*)alloc((size_t)N * HH * 2);
  float* f1_f32          = (float*)alloc((size_t)N * HH * 4);
  unsigned short* packed = (unsigned short*)alloc((size_t)6 * 16384 * 2);
  float* fOut = (float*)d_out;

  const int cblocks = (N + 63) / 64;      // 4 waves x 16 rows per 256-thr block
  const int eblocks = (E + 255) / 256;
  const int ablocks = (N + 3) / 4;
  const int sblocks = (N + 1023) / 1024;  // <= 64 for N <= 65536

  // weight packing
  pack_kernel<<<dim3(64, 6), 256, 0, stream>>>(Wc1, Wc2, Wm1, Wm2, Wp1, Wp2, packed);

  // CSR build (rank-based, fill is atomic-free)
  hipMemsetAsync(cnt, 0, (size_t)N * 4, stream);
  count_kernel<<<eblocks, 256, 0, stream>>>(dst, cnt, rank, E);
  scan1_kernel<<<sblocks, 1024, 0, stream>>>(cnt, rowptr, bsum, dinv, N);
  scan2_kernel<<<1, 64, 0, stream>>>(bsum, sblocks, rowptr, N, E);
  scan3_kernel<<<sblocks, 1024, 0, stream>>>(rowptr, bsum, N);
  fill_kernel<<<eblocks, 256, 0, stream>>>(src, dst, rowptr, rank, dinv, csr, E);

  // conv1: h_bf = bf16(x @ Wc1)
  gemm_conv<<<cblocks, 256, 0, stream>>>(x, packed + 0 * 16384, h_bf, N);
  // agg1: f1 = leaky(agg(h_bf)+self+bc1)  [fp32]
  agg_kernel<0, 0><<<ablocks, 256, 0, stream>>>(h_bf, rowptr, csr, dinv, bc1, nullptr, f1_f32, N);
  // conv2: t2 = bf16(f1 @ Wc2)
  gemm_conv<<<cblocks, 256, 0, stream>>>(f1_f32, packed + 1 * 16384, t2_bf, N);
  // agg2: f2 = leaky(agg(t2)+self+bc2+f1)  [bf16 — only consumed as bf16]
  agg_kernel<1, 1><<<ablocks, 256, 0, stream>>>(t2_bf, rowptr, csr, dinv, bc2, f1_f32, f2_bf, N);
  // fusedMLP: MLP + interp + proj -> d_out
  fusedMLP<<<cblocks, 256, 0, stream>>>(f2_bf,
                                        packed + 2 * 16384, packed + 3 * 16384,
                                        packed + 4 * 16384, packed + 5 * 16384,
                                        bm1, bm2, bp1, bp2, gen, fOut, N);
}